// Round 15
// baseline (332.310 us; speedup 1.0000x reference)
//
#include <hip/hip_runtime.h>
#include <cstdint>

#define RASTN 256
#define FARV 10.0f
#define FARBITS 0x41200000u   // bits of 10.0f
#define SPLIT 4               // measured optimum (R13: 4->103us; R14: 2->121us knee)
#define NBUCK 1024            // counting-sort buckets; width 1/512 (exact dyadic)
#define NINITY 8              // extra prep blocks per batch for zbuf memset

__device__ __forceinline__ float gval(int i) {
    // g = 2*(i+0.5)/256 - 1  -- exact in f32 (multiples of 1/256)
    return (2.0f * ((float)i + 0.5f)) / 256.0f - 1.0f;
}

// ============ Kernel 1: project + prep + counting-sort + inits (grid B x NINITY) =
// y > 0 blocks: memset a slice of this batch's z-buffer to FAR, then exit.
// y == 0 block: mm/tcnt init + project + prep + counting sort + scatter.
// rec q0 = (cx, cy, by-cy, cx-bx)
//     q1 = (cy-ay, ax-cx, rcp(dens), rcp(za))      [rcp approx, filter-only]
//     q2 = (dens, za, zb, zc)                      [exact path]
//     q3 = (pack bbox bits, minz*(1-4e-4), rcp(zb), rcp(zc))
// sax[rank] = (pack, key bits) keys non-decreasing (bucket LB, exact <= minz);
// dead triangles -> bucket NBUCK-1, key 3e38 (kp=false -> uncovered tiles can break).
__global__ __launch_bounds__(1024) void prep_sort_kernel(
    const float* __restrict__ verts, const int* __restrict__ faces,
    const float* __restrict__ Km, const float* __restrict__ Rm,
    const float* __restrict__ tm, const float* __restrict__ dm,
    float4* __restrict__ rec, uint2* __restrict__ sax, unsigned short* __restrict__ stri,
    unsigned int* __restrict__ zbits, unsigned int* __restrict__ mm,
    unsigned int* __restrict__ tcnt, float* __restrict__ uvzg,
    int V, int F, int F2, int B, int npix)
{
#pragma clang fp contract(off)
    __shared__ float s_uvz[1024*3];
    __shared__ unsigned int s_pk[4096];
    __shared__ unsigned short s_bk[4096];
    __shared__ unsigned int s_hist[NBUCK], s_cnt2[NBUCK];
    int b = blockIdx.x, y = blockIdx.y, tid = threadIdx.x;
    // ---- parallel z-buffer init: each y-block memsets 1/NINITY of this batch ----
    uint4* zb4 = (uint4*)(zbits + (size_t)b * npix);
    int n4 = npix >> 2;
    int sl0 = (n4 * y) / NINITY, sl1 = (n4 * (y + 1)) / NINITY;
    for (int i = sl0 + tid; i < sl1; i += 1024)
        zb4[i] = make_uint4(FARBITS, FARBITS, FARBITS, FARBITS);
    if (y > 0) return;
    if (tid == 0) { mm[2*b] = 0u; mm[2*b+1] = FARBITS; }  // minmax accumulators
    if (tid < 256) tcnt[b*256 + tid] = 0u;                // per-tile arrival counters
    for (int i = tid; i < NBUCK; i += 1024) s_hist[i] = 0u;
    // ---- project (bit-exact replica of reference _project) ----
    bool inlds = (V <= 1024);
    const float* R = Rm + b*9; const float* K = Km + b*9;
    const float* t = tm + b*3; const float* d = dm + b*5;
    for (int v = tid; v < V; v += 1024) {
        float vx = verts[((size_t)b*V + v)*3+0];
        float vy = verts[((size_t)b*V + v)*3+1];
        float vz = verts[((size_t)b*V + v)*3+2];
        float cxm = ((vx*R[0] + vy*R[1]) + vz*R[2]) + t[0];
        float cym = ((vx*R[3] + vy*R[4]) + vz*R[5]) + t[1];
        float czm = ((vx*R[6] + vy*R[7]) + vz*R[8]) + t[2];
        float zd = czm + 1e-9f;
        float x_ = cxm / zd;
        float y_ = cym / zd;
        float k1 = d[0], k2 = d[1], p1 = d[2], p2 = d[3], k3 = d[4];
        float r2   = (x_*x_) + (y_*y_);
        float r2_2 = r2 * r2;
        float r2_3 = r2 * r2_2;
        float radial = ((1.0f + k1*r2) + k2*r2_2) + k3*r2_3;
        float x__ = ((x_*radial) + (((2.0f*p1)*x_)*y_)) + (p2*(r2 + 2.0f*(x_*x_)));
        float y__ = ((y_*radial) + (p1*(r2 + 2.0f*(y_*y_)))) + (((2.0f*p2)*x_)*y_);
        float up = ((x__*K[0]) + (y__*K[1])) + (1.0f*K[2]);
        float vp = ((x__*K[3]) + (y__*K[4])) + (1.0f*K[5]);
        vp = 256.0f - vp;
        float un = (2.0f*(up - 128.0f)) / 256.0f;
        float vn = (2.0f*(vp - 128.0f)) / 256.0f;
        if (inlds) { s_uvz[v*3+0]=un; s_uvz[v*3+1]=vn; s_uvz[v*3+2]=czm; }
        else { uvzg[((size_t)b*V+v)*3+0]=un; uvzg[((size_t)b*V+v)*3+1]=vn; uvzg[((size_t)b*V+v)*3+2]=czm; }
    }
    __syncthreads();
    const float* ub = inlds ? s_uvz : (uvzg + (size_t)b*V*3);
    const int* fb = faces + (size_t)b * F * 3;
    float4* rb = rec + (size_t)b * F2 * 4;
    bool stash = (F2 <= 4096);
    // ---- prep + histogram ----
    for (int j = tid; j < F2; j += 1024) {
        int i0, i1, i2;
        if (j < F) { i0 = fb[j*3+0]; i1 = fb[j*3+1]; i2 = fb[j*3+2]; }
        else { int jj = j - F; i0 = fb[jj*3+2]; i1 = fb[jj*3+1]; i2 = fb[jj*3+0]; }
        float ax = ub[i0*3+0], ay = ub[i0*3+1], az = ub[i0*3+2];
        float bx = ub[i1*3+0], by = ub[i1*3+1], bz = ub[i1*3+2];
        float cx = ub[i2*3+0], cy = ub[i2*3+1], cz = ub[i2*3+2];
        float den = (bx-ax)*(cy-ay) - (by-ay)*(cx-ax);
        bool ok = fabsf(den) > 1e-8f;
        float dens = ok ? den : 1.0f;
        bool alive = ok && (az > 1e-8f) && (bz > 1e-8f) && (cz > 1e-8f);
        float za = (az > 1e-8f) ? az : 1.0f;
        float zb = (bz > 1e-8f) ? bz : 1.0f;
        float zc = (cz > 1e-8f) ? cz : 1.0f;
        float mnx = fminf(ax, fminf(bx, cx));
        float mxx = fmaxf(ax, fmaxf(bx, cx));
        float mny = fminf(ay, fminf(by, cy));
        float mxy = fmaxf(ay, fmaxf(by, cy));
        float m = 1e-3f + 1e-6f*((fabsf(mnx)+fabsf(mxx))+(fabsf(mny)+fabsf(mxy)));
        mnx -= m; mxx += m; mny -= m; mxy += m;
        if (!(mxx >= -1.0f) || !(mnx <= 1.0f) || !(mxy >= -1.0f) || !(mny <= 1.0f)) alive = false;
        int ic0 = 1, ic1 = 0, ir0 = 1, ir1 = 0;
        float minz = 3e38f;
        if (alive) {
            float lx = fmaxf(mnx, -1.5f), hx = fminf(mxx, 1.5f);
            float ly = fmaxf(mny, -1.5f), hy = fminf(mxy, 1.5f);
            ic0 = (int)floorf((lx + 1.0f) * 128.0f - 0.5f);
            ic1 = (int)ceilf ((hx + 1.0f) * 128.0f - 0.5f);
            ir0 = (int)floorf((ly + 1.0f) * 128.0f - 0.5f);
            ir1 = (int)ceilf ((hy + 1.0f) * 128.0f - 0.5f);
            ic0 = ic0 < 0 ? 0 : ic0;  ir0 = ir0 < 0 ? 0 : ir0;
            ic1 = ic1 > 255 ? 255 : ic1;  ir1 = ir1 > 255 ? 255 : ir1;
            if (ic0 > ic1 || ir0 > ir1) { ic0 = 1; ic1 = 0; ir0 = 1; ir1 = 0; minz = 3e38f; }
            else minz = fminf(za, fminf(zb, zc)) * (1.0f - 4e-4f);  // conservative early-z key
        }
        float minzv = fminf(za, fminf(zb, zc));
        float maxzv = fmaxf(za, fmaxf(zb, zc));
        float rd = __builtin_amdgcn_rcpf(dens);
        float ra, rbz, rc;
        if (minzv > 1e-2f && maxzv < 100.0f * minzv) {
            ra  = __builtin_amdgcn_rcpf(za);
            rbz = __builtin_amdgcn_rcpf(zb);
            rc  = __builtin_amdgcn_rcpf(zc);
        } else {
            ra = rbz = rc = __builtin_huge_valf();   // filters disabled -> exact path
        }
        unsigned int pack = (unsigned int)(ic0 | (ic1 << 8) | (ir0 << 16) | (ir1 << 24));
        int bk = NBUCK - 1;                          // dead -> last bucket (huge key)
        if (minz < 1e30f) {
            bk = (int)(minz * 512.0f);               // floor; bucket LB = bk/512 exact
            bk = bk < 0 ? 0 : (bk > NBUCK-2 ? NBUCK-2 : bk);
        }
        size_t base = (size_t)j * 4;
        rb[base+0] = make_float4(cx, cy, by - cy, cx - bx);
        rb[base+1] = make_float4(cy - ay, ax - cx, rd, ra);
        rb[base+2] = make_float4(dens, za, zb, zc);
        rb[base+3] = make_float4(__uint_as_float(pack), minz, rbz, rc);
        atomicAdd(&s_hist[bk], 1u);
        if (stash) { s_pk[j] = pack; s_bk[j] = (unsigned short)bk; }
    }
    __syncthreads();
    // ---- exclusive prefix over NBUCK buckets (Hillis-Steele in LDS) ----
    for (int i = tid; i < NBUCK; i += 1024) s_cnt2[i] = s_hist[i];
    __syncthreads();
    for (int st = 1; st < NBUCK; st <<= 1) {
        unsigned int v = 0;
        if (tid < NBUCK && tid >= st) v = s_cnt2[tid - st];
        __syncthreads();
        if (tid < NBUCK && tid >= st) s_cnt2[tid] += v;
        __syncthreads();
    }
    if (tid < NBUCK) s_cnt2[tid] -= s_hist[tid];     // exclusive offsets
    __syncthreads();
    // ---- scatter (order within bucket arbitrary; key = bucket LB -> conservative;
    //       final zbuf is a set-min => order-independent, exact) ----
    uint2* sxb = sax + (size_t)b * F2;
    unsigned short* stb = stri + (size_t)b * F2;
    for (int j = tid; j < F2; j += 1024) {
        unsigned int pack; int bk;
        if (stash) { pack = s_pk[j]; bk = (int)s_bk[j]; }
        else {
            float4 q3 = rb[(size_t)j*4+3];
            pack = __float_as_uint(q3.x);
            float mz = q3.y;
            bk = NBUCK - 1;
            if (mz < 1e30f) { bk = (int)(mz * 512.0f); bk = bk < 0 ? 0 : (bk > NBUCK-2 ? NBUCK-2 : bk); }
        }
        float key = (bk == NBUCK-1) ? 3e38f : (float)bk * (1.0f/512.0f);  // exact dyadic LB
        int pos = (int)atomicAdd(&s_cnt2[bk], 1u);
        sxb[pos] = make_uint2(pack, __float_as_uint(key));
        stb[pos] = (unsigned short)j;
    }
}

// ============ Kernel 2: tile raster, SPLIT blocks/tile, shared per-pixel z =======
// Last-arriving split per tile also writes mask + folds the tile into mm.
__global__ __launch_bounds__(256) void raster_kernel(
    const float4* __restrict__ rec, const uint2* __restrict__ sax,
    const unsigned short* __restrict__ stri, unsigned int* __restrict__ zbits,
    float* __restrict__ mask, unsigned int* __restrict__ mm,
    unsigned int* __restrict__ tcnt, int F2)
{
#pragma clang fp contract(off)
    __shared__ float4 sh[256];                 // 64 tris x 4 records
    __shared__ float s_mz[64];
    __shared__ unsigned short s_list[256];
    __shared__ int s_wk[4], s_kk[4], s_wo[4];
    __shared__ int s_tot, s_kc, s_last;
    __shared__ float s_tzmax, s_red[4], s_red2[4];
    int zz = blockIdx.z;
    int b = zz / SPLIT, sp = zz - b*SPLIT;
    int tc = blockIdx.x, tr = blockIdx.y;
    int tid = threadIdx.x, lane = tid & 63, wv = tid >> 6;
    int tx = tid & 15, ty = tid >> 4;
    int col = tc*16 + tx, row = tr*16 + ty;
    float X = gval(col), Y = gval(row);
    int pc0 = tc*16, pc1 = pc0+15, pr0 = tr*16, pr1 = pr0+15;
    const float4* rb = rec + (size_t)b * F2 * 4;
    const uint2* sxb = sax + (size_t)b * F2;
    const unsigned short* stb = stri + (size_t)b * F2;
    size_t pix = ((size_t)b*RASTN + row)*RASTN + col;
    unsigned int* zp_g = zbits + pix;
    float zmin = FARV;
    float pushed = FARV;     // min value known to already be in zbits[pix]
    if (tid == 0) s_tzmax = FARV;
    __syncthreads();
    int nch = (F2 + 256*SPLIT - 1) / (256*SPLIT);
    for (int c = 0; c < nch; ++c) {
        // rank interleaved at fine granularity: all splits converge on the front
        int s = (c*256 + tid)*SPLIT + sp;
        bool kp = false, sv = false; unsigned int tri = 0;
        if (s < F2) {
            uint2 a = sxb[s];
            float kf = __uint_as_float(a.y);
            kp = !(kf > s_tzmax);                  // conservative early-z (key <= minz)
            if (kp) {
                int pk = (int)a.x;
                int ic0 = pk & 255, ic1 = (pk >> 8) & 255;
                int ir0 = (pk >> 16) & 255, ir1 = (pk >> 24) & 255;
                sv = (ic0 <= ic1) && (ic0 <= pc1) && (ic1 >= pc0) && (ir0 <= pr1) && (ir1 >= pr0);
                if (sv) tri = stb[s];
            }
        }
        unsigned long long bs = __ballot(sv ? 1 : 0);
        unsigned long long bk = __ballot(kp ? 1 : 0);
        int pfx = __popcll(bs & ((1ull << lane) - 1ull));
        if (lane == 0) { s_wk[wv] = __popcll(bs); s_kk[wv] = __popcll(bk); }
        __syncthreads();
        if (tid == 0) {
            int acc = 0;
            for (int q = 0; q < 4; ++q) { s_wo[q] = acc; acc += s_wk[q]; }
            s_tot = acc;
            s_kc = s_kk[0] + s_kk[1] + s_kk[2] + s_kk[3];
        }
        __syncthreads();
        if (sv) s_list[s_wo[wv] + pfx] = (unsigned short)tri;
        int kcnt = s_kc, n = s_tot;
        if (kcnt == 0) break;   // keys non-decreasing: all remaining > tzmax
        for (int g = 0; g < n; g += 64) {
            __syncthreads();
            int cnt2 = (n - g) < 64 ? (n - g) : 64;
            if (tid < cnt2*4) {
                unsigned int t4 = s_list[g + (tid >> 2)];
                float4 f = rb[(size_t)t4*4 + (tid & 3)];
                sh[tid] = f;
                if ((tid & 3) == 3) s_mz[tid >> 2] = f.y;
            }
            __syncthreads();
            // ---- pull shared z: other splits' published mins tighten early-z.
            // zbits only decreases; pulled >= final -> skips are conservative.
            {
                float zg = __uint_as_float(__hip_atomic_load(
                    zp_g, __ATOMIC_RELAXED, __HIP_MEMORY_SCOPE_AGENT));
                pushed = fminf(pushed, zg);
                zmin = fminf(zmin, zg);
            }
            for (int i = 0; i < cnt2; ++i) {
                float mz = s_mz[i];
                if (mz > zmin) continue;           // per-pixel early-z (safe: zp >= mz)
                float4 q3 = sh[i*4+3];
                int pk = __float_as_int(q3.x);
                int ic0 = pk & 255, ic1 = (pk >> 8) & 255;
                int ir0 = (pk >> 16) & 255, ir1 = (pk >> 24) & 255;
                if (col < ic0 || col > ic1 || row < ir0 || row > ir1) continue;
                float4 q0 = sh[i*4+0];
                float4 q1 = sh[i*4+1];
                float xc = X - q0.x;
                float yc = Y - q0.y;
                float e0 = (q0.z*xc) + (q0.w*yc);  // w0 numerator, bit-exact vs ref
                float e1 = (q1.x*xc) + (q1.y*yc);  // w1 numerator
                float rd = q1.z;
                float sgn = copysignf(1.0f, rd);   // sign(rd) == sign(dens)
                float s0 = e0*sgn, s1 = e1*sgn;
                float w0a = e0*rd, w1a = e1*rd;    // approx w (filter only)
                float w2a = (1.0f - w0a) - w1a;
                float epsu = 1e-4f*((1.0f + fabsf(w0a)) + fabsf(w1a));
                if (s0 > -1e-30f && s1 > -1e-30f && w2a > -epsu) {
                    float inva = ((w0a*q1.w) + (w1a*q3.z)) + (w2a*q3.w);
                    float zpa = __builtin_amdgcn_rcpf(inva);
                    bool clearly = (s0 > 0.0f) && (s1 > 0.0f) && (w2a > epsu) && (inva > 1e-6f);
                    // clearly-valid + approx-zp above zmin (w/ margin) provably
                    // cannot change the exact min -> skip the 6 IEEE divides
                    if (!clearly || zpa < zmin*1.001f) {
                        float4 q2 = sh[i*4+2];
                        float dens = q2.x;
                        float w0 = e0 / dens;      // IEEE div == ref
                        float w1 = e1 / dens;
                        float w2 = (1.0f - w0) - w1;
                        float inv = ((w0 / q2.y) + (w1 / q2.z)) + (w2 / q2.w);
                        if ((w0 >= 0.0f) && (w1 >= 0.0f) && (w2 >= 0.0f) && (inv > 1e-8f)) {
                            float zp = 1.0f / inv; // exact div == ref zp
                            zmin = fminf(zmin, zp);
                        }
                    }
                }
            }
            // ---- push improvement so other splits can skip their warm-up
            if (zmin < pushed) {
                atomicMin(zp_g, __float_as_uint(zmin));   // bit-monotone positive floats
                pushed = zmin;
            }
        }
        if (n > 0) {
            // tile zmax refresh: only shrinks -> stays a conservative upper bound
            float zx = zmin;
            for (int o = 32; o; o >>= 1) zx = fmaxf(zx, __shfl_xor(zx, o));
            if (lane == 0) s_red[wv] = zx;
        }
        __syncthreads();
        if (n > 0 && tid == 0)
            s_tzmax = fminf(s_tzmax,
                fmaxf(fmaxf(s_red[0], s_red[1]), fmaxf(s_red[2], s_red[3])));
        __syncthreads();
    }
    if (zmin < pushed)
        atomicMin(zp_g, __float_as_uint(zmin));   // final publish
    // ---- arrival: last split per tile writes mask + folds tile into mm ----
    __syncthreads();
    if (tid == 0) {
        __threadfence();                           // my publishes visible before count
        unsigned int old = __hip_atomic_fetch_add(
            tcnt + b*256 + (tr*16 + tc), 1u, __ATOMIC_ACQ_REL, __HIP_MEMORY_SCOPE_AGENT);
        s_last = (old == SPLIT - 1) ? 1 : 0;
    }
    __syncthreads();
    if (s_last) {
        __threadfence();                           // see all other splits' publishes
        float z = __uint_as_float(__hip_atomic_load(
            zp_g, __ATOMIC_RELAXED, __HIP_MEMORY_SCOPE_AGENT));   // final value
        mask[pix] = (z < FARV) ? 1.0f : 0.0f;      // cover == any valid hit (z < FAR)
        float nb = (z == FARV) ? 0.0f : z;         // (1-img_inf)*img
        float a = nb, mn = z;
        for (int o = 32; o; o >>= 1) {
            a  = fmaxf(a,  __shfl_xor(a,  o));
            mn = fminf(mn, __shfl_xor(mn, o));
        }
        if (lane == 0) { s_red[wv] = a; s_red2[wv] = mn; }
        __syncthreads();
        if (tid == 0) {
            float bmx = fmaxf(fmaxf(s_red[0], s_red[1]), fmaxf(s_red[2], s_red[3]));
            float bmn = fminf(fminf(s_red2[0], s_red2[1]), fminf(s_red2[2], s_red2[3]));
            atomicMax(mm + 2*b,     __float_as_uint(bmx));   // positive floats: bit-monotone
            atomicMin(mm + 2*b + 1, __float_as_uint(bmn));
        }
    }
}

// ============ Kernel 3: normalize depth in place =================================
__global__ __launch_bounds__(256) void final_kernel(
    float* __restrict__ zdep, const unsigned int* __restrict__ mm, int npix, int total)
{
#pragma clang fp contract(off)
    int idx = blockIdx.x*256 + threadIdx.x;
    if (idx >= total) return;
    int b = idx / npix;
    float mx = __uint_as_float(mm[2*b]);
    float mn = __uint_as_float(mm[2*b + 1]);
    float z = zdep[idx];
    float nd = (mx - z) / ((mx - mn) + 1e-4f);
    float cv = nd;
    cv = (cv < 0.0f) ? 0.0f : cv;
    cv = (cv > 1.0f) ? 1.0f : cv;
    zdep[idx] = cv;
}

extern "C" void kernel_launch(void* const* d_in, const int* in_sizes, int n_in,
                              void* d_out, int out_size, void* d_ws, size_t ws_size,
                              hipStream_t stream)
{
    const float* verts = (const float*)d_in[0];
    const int*   faces = (const int*)d_in[1];
    const float* Km    = (const float*)d_in[2];
    const float* Rm    = (const float*)d_in[3];
    const float* tm    = (const float*)d_in[4];
    const float* dm    = (const float*)d_in[5];
    float* out = (float*)d_out;

    int B  = in_sizes[2] / 9;          // intr is B*3*3
    int V  = in_sizes[0] / (3 * B);
    int F  = in_sizes[1] / (3 * B);
    int F2 = 2 * F;
    int npix = RASTN * RASTN;

    char* ws = (char*)d_ws;
    size_t off = 0;
    float4* rec = (float4*)(ws + off);
    off = (off + (size_t)B * F2 * 4 * sizeof(float4) + 255) & ~(size_t)255;
    uint2* sax = (uint2*)(ws + off);
    off = (off + (size_t)B * F2 * sizeof(uint2) + 255) & ~(size_t)255;
    unsigned short* stri = (unsigned short*)(ws + off);
    off = (off + (size_t)B * F2 * sizeof(unsigned short) + 255) & ~(size_t)255;
    float* uvzg = (float*)(ws + off);
    off = (off + (size_t)B * V * 3 * sizeof(float) + 255) & ~(size_t)255;
    unsigned int* mm = (unsigned int*)(ws + off);
    off = (off + (size_t)B * 2 * sizeof(unsigned int) + 255) & ~(size_t)255;
    unsigned int* tcnt = (unsigned int*)(ws + off);

    unsigned int* zbits = (unsigned int*)out;        // depth region doubles as zbuf
    float* mask = out + (size_t)B * npix;

    dim3 pgrid(B, NINITY);
    prep_sort_kernel<<<pgrid, 1024, 0, stream>>>(
        verts, faces, Km, Rm, tm, dm, rec, sax, stri, zbits, mm, tcnt, uvzg,
        V, F, F2, B, npix);
    dim3 rgrid(16, 16, B * SPLIT);
    raster_kernel<<<rgrid, 256, 0, stream>>>(rec, sax, stri, zbits, mask, mm, tcnt, F2);
    final_kernel<<<(B * npix + 255) / 256, 256, 0, stream>>>((float*)zbits, mm, npix, B * npix);
}

// Round 16
// 202.866 us; speedup vs baseline: 1.6381x; 1.6381x over previous
//
#include <hip/hip_runtime.h>
#include <cstdint>

#define RASTN 256
#define FARV 10.0f
#define FARBITS 0x41200000u   // bits of 10.0f
#define SPLIT 4               // measured optimum (R13: 4->103us; R14: 2->121us knee; R9: 8->150us)
#define NBUCK 1024            // counting-sort buckets; width 1/512 (exact dyadic)
#define NINITY 8              // extra prep blocks per batch for zbuf memset

__device__ __forceinline__ float gval(int i) {
    // g = 2*(i+0.5)/256 - 1  -- exact in f32 (multiples of 1/256)
    return (2.0f * ((float)i + 0.5f)) / 256.0f - 1.0f;
}

// ============ Kernel 1: project + prep + counting-sort + inits (grid B x NINITY) =
// y > 0 blocks: memset a slice of this batch's z-buffer to FAR, then exit.
// y == 0 block: project + prep + counting sort + scatter.
// rec q0 = (cx, cy, by-cy, cx-bx)
//     q1 = (cy-ay, ax-cx, rcp(dens), rcp(za))      [rcp approx, filter-only]
//     q2 = (dens, za, zb, zc)                      [exact path]
//     q3 = (pack bbox bits, minz*(1-4e-4), rcp(zb), rcp(zc))
// sax[rank] = (pack, key bits) keys non-decreasing (bucket LB, exact <= minz);
// dead triangles -> bucket NBUCK-1, key 3e38 (kp=false -> uncovered tiles can break).
__global__ __launch_bounds__(1024) void prep_sort_kernel(
    const float* __restrict__ verts, const int* __restrict__ faces,
    const float* __restrict__ Km, const float* __restrict__ Rm,
    const float* __restrict__ tm, const float* __restrict__ dm,
    float4* __restrict__ rec, uint2* __restrict__ sax, unsigned short* __restrict__ stri,
    unsigned int* __restrict__ zbits, float* __restrict__ uvzg,
    int V, int F, int F2, int B, int npix)
{
#pragma clang fp contract(off)
    __shared__ float s_uvz[1024*3];
    __shared__ unsigned int s_pk[4096];
    __shared__ unsigned short s_bk[4096];
    __shared__ unsigned int s_hist[NBUCK], s_cnt2[NBUCK];
    int b = blockIdx.x, y = blockIdx.y, tid = threadIdx.x;
    // ---- parallel z-buffer init: each y-block memsets 1/NINITY of this batch ----
    uint4* zb4 = (uint4*)(zbits + (size_t)b * npix);
    int n4 = npix >> 2;
    int sl0 = (n4 * y) / NINITY, sl1 = (n4 * (y + 1)) / NINITY;
    for (int i = sl0 + tid; i < sl1; i += 1024)
        zb4[i] = make_uint4(FARBITS, FARBITS, FARBITS, FARBITS);
    if (y > 0) return;
    for (int i = tid; i < NBUCK; i += 1024) s_hist[i] = 0u;
    // ---- project (bit-exact replica of reference _project) ----
    bool inlds = (V <= 1024);
    const float* R = Rm + b*9; const float* K = Km + b*9;
    const float* t = tm + b*3; const float* d = dm + b*5;
    for (int v = tid; v < V; v += 1024) {
        float vx = verts[((size_t)b*V + v)*3+0];
        float vy = verts[((size_t)b*V + v)*3+1];
        float vz = verts[((size_t)b*V + v)*3+2];
        float cxm = ((vx*R[0] + vy*R[1]) + vz*R[2]) + t[0];
        float cym = ((vx*R[3] + vy*R[4]) + vz*R[5]) + t[1];
        float czm = ((vx*R[6] + vy*R[7]) + vz*R[8]) + t[2];
        float zd = czm + 1e-9f;
        float x_ = cxm / zd;
        float y_ = cym / zd;
        float k1 = d[0], k2 = d[1], p1 = d[2], p2 = d[3], k3 = d[4];
        float r2   = (x_*x_) + (y_*y_);
        float r2_2 = r2 * r2;
        float r2_3 = r2 * r2_2;
        float radial = ((1.0f + k1*r2) + k2*r2_2) + k3*r2_3;
        float x__ = ((x_*radial) + (((2.0f*p1)*x_)*y_)) + (p2*(r2 + 2.0f*(x_*x_)));
        float y__ = ((y_*radial) + (p1*(r2 + 2.0f*(y_*y_)))) + (((2.0f*p2)*x_)*y_);
        float up = ((x__*K[0]) + (y__*K[1])) + (1.0f*K[2]);
        float vp = ((x__*K[3]) + (y__*K[4])) + (1.0f*K[5]);
        vp = 256.0f - vp;
        float un = (2.0f*(up - 128.0f)) / 256.0f;
        float vn = (2.0f*(vp - 128.0f)) / 256.0f;
        if (inlds) { s_uvz[v*3+0]=un; s_uvz[v*3+1]=vn; s_uvz[v*3+2]=czm; }
        else { uvzg[((size_t)b*V+v)*3+0]=un; uvzg[((size_t)b*V+v)*3+1]=vn; uvzg[((size_t)b*V+v)*3+2]=czm; }
    }
    __syncthreads();
    const float* ub = inlds ? s_uvz : (uvzg + (size_t)b*V*3);
    const int* fb = faces + (size_t)b * F * 3;
    float4* rb = rec + (size_t)b * F2 * 4;
    bool stash = (F2 <= 4096);
    // ---- prep + histogram ----
    for (int j = tid; j < F2; j += 1024) {
        int i0, i1, i2;
        if (j < F) { i0 = fb[j*3+0]; i1 = fb[j*3+1]; i2 = fb[j*3+2]; }
        else { int jj = j - F; i0 = fb[jj*3+2]; i1 = fb[jj*3+1]; i2 = fb[jj*3+0]; }
        float ax = ub[i0*3+0], ay = ub[i0*3+1], az = ub[i0*3+2];
        float bx = ub[i1*3+0], by = ub[i1*3+1], bz = ub[i1*3+2];
        float cx = ub[i2*3+0], cy = ub[i2*3+1], cz = ub[i2*3+2];
        float den = (bx-ax)*(cy-ay) - (by-ay)*(cx-ax);
        bool ok = fabsf(den) > 1e-8f;
        float dens = ok ? den : 1.0f;
        bool alive = ok && (az > 1e-8f) && (bz > 1e-8f) && (cz > 1e-8f);
        float za = (az > 1e-8f) ? az : 1.0f;
        float zb = (bz > 1e-8f) ? bz : 1.0f;
        float zc = (cz > 1e-8f) ? cz : 1.0f;
        float mnx = fminf(ax, fminf(bx, cx));
        float mxx = fmaxf(ax, fmaxf(bx, cx));
        float mny = fminf(ay, fminf(by, cy));
        float mxy = fmaxf(ay, fmaxf(by, cy));
        float m = 1e-3f + 1e-6f*((fabsf(mnx)+fabsf(mxx))+(fabsf(mny)+fabsf(mxy)));
        mnx -= m; mxx += m; mny -= m; mxy += m;
        if (!(mxx >= -1.0f) || !(mnx <= 1.0f) || !(mxy >= -1.0f) || !(mny <= 1.0f)) alive = false;
        int ic0 = 1, ic1 = 0, ir0 = 1, ir1 = 0;
        float minz = 3e38f;
        if (alive) {
            float lx = fmaxf(mnx, -1.5f), hx = fminf(mxx, 1.5f);
            float ly = fmaxf(mny, -1.5f), hy = fminf(mxy, 1.5f);
            ic0 = (int)floorf((lx + 1.0f) * 128.0f - 0.5f);
            ic1 = (int)ceilf ((hx + 1.0f) * 128.0f - 0.5f);
            ir0 = (int)floorf((ly + 1.0f) * 128.0f - 0.5f);
            ir1 = (int)ceilf ((hy + 1.0f) * 128.0f - 0.5f);
            ic0 = ic0 < 0 ? 0 : ic0;  ir0 = ir0 < 0 ? 0 : ir0;
            ic1 = ic1 > 255 ? 255 : ic1;  ir1 = ir1 > 255 ? 255 : ir1;
            if (ic0 > ic1 || ir0 > ir1) { ic0 = 1; ic1 = 0; ir0 = 1; ir1 = 0; minz = 3e38f; }
            else minz = fminf(za, fminf(zb, zc)) * (1.0f - 4e-4f);  // conservative early-z key
        }
        float minzv = fminf(za, fminf(zb, zc));
        float maxzv = fmaxf(za, fmaxf(zb, zc));
        float rd = __builtin_amdgcn_rcpf(dens);
        float ra, rbz, rc;
        if (minzv > 1e-2f && maxzv < 100.0f * minzv) {
            ra  = __builtin_amdgcn_rcpf(za);
            rbz = __builtin_amdgcn_rcpf(zb);
            rc  = __builtin_amdgcn_rcpf(zc);
        } else {
            ra = rbz = rc = __builtin_huge_valf();   // filters disabled -> exact path
        }
        unsigned int pack = (unsigned int)(ic0 | (ic1 << 8) | (ir0 << 16) | (ir1 << 24));
        int bk = NBUCK - 1;                          // dead -> last bucket (huge key)
        if (minz < 1e30f) {
            bk = (int)(minz * 512.0f);               // floor; bucket LB = bk/512 exact
            bk = bk < 0 ? 0 : (bk > NBUCK-2 ? NBUCK-2 : bk);
        }
        size_t base = (size_t)j * 4;
        rb[base+0] = make_float4(cx, cy, by - cy, cx - bx);
        rb[base+1] = make_float4(cy - ay, ax - cx, rd, ra);
        rb[base+2] = make_float4(dens, za, zb, zc);
        rb[base+3] = make_float4(__uint_as_float(pack), minz, rbz, rc);
        atomicAdd(&s_hist[bk], 1u);
        if (stash) { s_pk[j] = pack; s_bk[j] = (unsigned short)bk; }
    }
    __syncthreads();
    // ---- exclusive prefix over NBUCK buckets (Hillis-Steele in LDS) ----
    for (int i = tid; i < NBUCK; i += 1024) s_cnt2[i] = s_hist[i];
    __syncthreads();
    for (int st = 1; st < NBUCK; st <<= 1) {
        unsigned int v = 0;
        if (tid < NBUCK && tid >= st) v = s_cnt2[tid - st];
        __syncthreads();
        if (tid < NBUCK && tid >= st) s_cnt2[tid] += v;
        __syncthreads();
    }
    if (tid < NBUCK) s_cnt2[tid] -= s_hist[tid];     // exclusive offsets
    __syncthreads();
    // ---- scatter (order within bucket arbitrary; key = bucket LB -> conservative;
    //       final zbuf is a set-min => order-independent, exact) ----
    uint2* sxb = sax + (size_t)b * F2;
    unsigned short* stb = stri + (size_t)b * F2;
    for (int j = tid; j < F2; j += 1024) {
        unsigned int pack; int bk;
        if (stash) { pack = s_pk[j]; bk = (int)s_bk[j]; }
        else {
            float4 q3 = rb[(size_t)j*4+3];
            pack = __float_as_uint(q3.x);
            float mz = q3.y;
            bk = NBUCK - 1;
            if (mz < 1e30f) { bk = (int)(mz * 512.0f); bk = bk < 0 ? 0 : (bk > NBUCK-2 ? NBUCK-2 : bk); }
        }
        float key = (bk == NBUCK-1) ? 3e38f : (float)bk * (1.0f/512.0f);  // exact dyadic LB
        int pos = (int)atomicAdd(&s_cnt2[bk], 1u);
        sxb[pos] = make_uint2(pack, __float_as_uint(key));
        stb[pos] = (unsigned short)j;
    }
}

// ============ Kernel 2: tile raster, SPLIT blocks/tile, shared per-pixel z =======
// (byte-identical to the R13 kernel measured at 103 us)
__global__ __launch_bounds__(256) void raster_kernel(
    const float4* __restrict__ rec, const uint2* __restrict__ sax,
    const unsigned short* __restrict__ stri, unsigned int* __restrict__ zbits,
    int F2)
{
#pragma clang fp contract(off)
    __shared__ float4 sh[256];                 // 64 tris x 4 records
    __shared__ float s_mz[64];
    __shared__ unsigned short s_list[256];
    __shared__ int s_wk[4], s_kk[4], s_wo[4];
    __shared__ int s_tot, s_kc;
    __shared__ float s_tzmax, s_red[4];
    int zz = blockIdx.z;
    int b = zz / SPLIT, sp = zz - b*SPLIT;
    int tc = blockIdx.x, tr = blockIdx.y;
    int tid = threadIdx.x, lane = tid & 63, wv = tid >> 6;
    int tx = tid & 15, ty = tid >> 4;
    int col = tc*16 + tx, row = tr*16 + ty;
    float X = gval(col), Y = gval(row);
    int pc0 = tc*16, pc1 = pc0+15, pr0 = tr*16, pr1 = pr0+15;
    const float4* rb = rec + (size_t)b * F2 * 4;
    const uint2* sxb = sax + (size_t)b * F2;
    const unsigned short* stb = stri + (size_t)b * F2;
    size_t pix = ((size_t)b*RASTN + row)*RASTN + col;
    unsigned int* zp_g = zbits + pix;
    float zmin = FARV;
    float pushed = FARV;     // min value known to already be in zbits[pix]
    if (tid == 0) s_tzmax = FARV;
    __syncthreads();
    int nch = (F2 + 256*SPLIT - 1) / (256*SPLIT);
    for (int c = 0; c < nch; ++c) {
        // rank interleaved at fine granularity: all splits converge on the front
        int s = (c*256 + tid)*SPLIT + sp;
        bool kp = false, sv = false; unsigned int tri = 0;
        if (s < F2) {
            uint2 a = sxb[s];
            float kf = __uint_as_float(a.y);
            kp = !(kf > s_tzmax);                  // conservative early-z (key <= minz)
            if (kp) {
                int pk = (int)a.x;
                int ic0 = pk & 255, ic1 = (pk >> 8) & 255;
                int ir0 = (pk >> 16) & 255, ir1 = (pk >> 24) & 255;
                sv = (ic0 <= ic1) && (ic0 <= pc1) && (ic1 >= pc0) && (ir0 <= pr1) && (ir1 >= pr0);
                if (sv) tri = stb[s];
            }
        }
        unsigned long long bs = __ballot(sv ? 1 : 0);
        unsigned long long bk = __ballot(kp ? 1 : 0);
        int pfx = __popcll(bs & ((1ull << lane) - 1ull));
        if (lane == 0) { s_wk[wv] = __popcll(bs); s_kk[wv] = __popcll(bk); }
        __syncthreads();
        if (tid == 0) {
            int acc = 0;
            for (int q = 0; q < 4; ++q) { s_wo[q] = acc; acc += s_wk[q]; }
            s_tot = acc;
            s_kc = s_kk[0] + s_kk[1] + s_kk[2] + s_kk[3];
        }
        __syncthreads();
        if (sv) s_list[s_wo[wv] + pfx] = (unsigned short)tri;
        int kcnt = s_kc, n = s_tot;
        if (kcnt == 0) break;   // keys non-decreasing: all remaining > tzmax
        for (int g = 0; g < n; g += 64) {
            __syncthreads();
            int cnt2 = (n - g) < 64 ? (n - g) : 64;
            if (tid < cnt2*4) {
                unsigned int t4 = s_list[g + (tid >> 2)];
                float4 f = rb[(size_t)t4*4 + (tid & 3)];
                sh[tid] = f;
                if ((tid & 3) == 3) s_mz[tid >> 2] = f.y;
            }
            __syncthreads();
            // ---- pull shared z: other splits' published mins tighten early-z.
            // zbits only decreases; pulled >= final -> skips are conservative.
            {
                float zg = __uint_as_float(__hip_atomic_load(
                    zp_g, __ATOMIC_RELAXED, __HIP_MEMORY_SCOPE_AGENT));
                pushed = fminf(pushed, zg);
                zmin = fminf(zmin, zg);
            }
            for (int i = 0; i < cnt2; ++i) {
                float mz = s_mz[i];
                if (mz > zmin) continue;           // per-pixel early-z (safe: zp >= mz)
                float4 q3 = sh[i*4+3];
                int pk = __float_as_int(q3.x);
                int ic0 = pk & 255, ic1 = (pk >> 8) & 255;
                int ir0 = (pk >> 16) & 255, ir1 = (pk >> 24) & 255;
                if (col < ic0 || col > ic1 || row < ir0 || row > ir1) continue;
                float4 q0 = sh[i*4+0];
                float4 q1 = sh[i*4+1];
                float xc = X - q0.x;
                float yc = Y - q0.y;
                float e0 = (q0.z*xc) + (q0.w*yc);  // w0 numerator, bit-exact vs ref
                float e1 = (q1.x*xc) + (q1.y*yc);  // w1 numerator
                float rd = q1.z;
                float sgn = copysignf(1.0f, rd);   // sign(rd) == sign(dens)
                float s0 = e0*sgn, s1 = e1*sgn;
                float w0a = e0*rd, w1a = e1*rd;    // approx w (filter only)
                float w2a = (1.0f - w0a) - w1a;
                float epsu = 1e-4f*((1.0f + fabsf(w0a)) + fabsf(w1a));
                if (s0 > -1e-30f && s1 > -1e-30f && w2a > -epsu) {
                    float inva = ((w0a*q1.w) + (w1a*q3.z)) + (w2a*q3.w);
                    float zpa = __builtin_amdgcn_rcpf(inva);
                    bool clearly = (s0 > 0.0f) && (s1 > 0.0f) && (w2a > epsu) && (inva > 1e-6f);
                    // clearly-valid + approx-zp above zmin (w/ margin) provably
                    // cannot change the exact min -> skip the 6 IEEE divides
                    if (!clearly || zpa < zmin*1.001f) {
                        float4 q2 = sh[i*4+2];
                        float dens = q2.x;
                        float w0 = e0 / dens;      // IEEE div == ref
                        float w1 = e1 / dens;
                        float w2 = (1.0f - w0) - w1;
                        float inv = ((w0 / q2.y) + (w1 / q2.z)) + (w2 / q2.w);
                        if ((w0 >= 0.0f) && (w1 >= 0.0f) && (w2 >= 0.0f) && (inv > 1e-8f)) {
                            float zp = 1.0f / inv; // exact div == ref zp
                            zmin = fminf(zmin, zp);
                        }
                    }
                }
            }
            // ---- push improvement so other splits can skip their warm-up
            if (zmin < pushed) {
                atomicMin(zp_g, __float_as_uint(zmin));   // bit-monotone positive floats
                pushed = zmin;
            }
        }
        if (n > 0) {
            // tile zmax refresh: only shrinks -> stays a conservative upper bound
            float zx = zmin;
            for (int o = 32; o; o >>= 1) zx = fmaxf(zx, __shfl_xor(zx, o));
            if (lane == 0) s_red[wv] = zx;
        }
        __syncthreads();
        if (n > 0 && tid == 0)
            s_tzmax = fminf(s_tzmax,
                fmaxf(fmaxf(s_red[0], s_red[1]), fmaxf(s_red[2], s_red[3])));
        __syncthreads();
    }
    if (zmin < pushed)
        atomicMin(zp_g, __float_as_uint(zmin));   // final publish
}

// ============ Kernel 3: fused post — one block per batch, block-internal only ====
// Pass 1: read z, write mask, reduce minmax across the block (shuffle + LDS).
// Pass 2: normalize in place (z re-read is L2-warm). No atomics, no fences.
__global__ __launch_bounds__(1024) void post_kernel(
    float* __restrict__ zdep, float* __restrict__ mask, int npix)
{
#pragma clang fp contract(off)
    __shared__ float smx[16], smn[16];
    __shared__ float s_mx, s_mn;
    int b = blockIdx.x, tid = threadIdx.x;
    int lane = tid & 63, wv = tid >> 6;
    float* p = zdep + (size_t)b * npix;
    float* mk = mask + (size_t)b * npix;
    float vmx = 0.0f, vmn = FARV;
    for (int i = tid; i < npix; i += 1024) {
        float z = p[i];
        mk[i] = (z < FARV) ? 1.0f : 0.0f;    // cover == any valid hit (z < FAR)
        float nb = (z == FARV) ? 0.0f : z;   // (1-img_inf)*img
        vmx = fmaxf(vmx, nb);
        vmn = fminf(vmn, z);
    }
    for (int o = 32; o; o >>= 1) {
        vmx = fmaxf(vmx, __shfl_xor(vmx, o));
        vmn = fminf(vmn, __shfl_xor(vmn, o));
    }
    if (lane == 0) { smx[wv] = vmx; smn[wv] = vmn; }
    __syncthreads();
    if (tid == 0) {
        float mx = smx[0], mn = smn[0];
        for (int k = 1; k < 16; ++k) { mx = fmaxf(mx, smx[k]); mn = fminf(mn, smn[k]); }
        s_mx = mx; s_mn = mn;
    }
    __syncthreads();
    float mx = s_mx, mn = s_mn;
    for (int i = tid; i < npix; i += 1024) {
        float z = p[i];
        float nd = (mx - z) / ((mx - mn) + 1e-4f);
        float cv = nd;
        cv = (cv < 0.0f) ? 0.0f : cv;
        cv = (cv > 1.0f) ? 1.0f : cv;
        p[i] = cv;
    }
}

extern "C" void kernel_launch(void* const* d_in, const int* in_sizes, int n_in,
                              void* d_out, int out_size, void* d_ws, size_t ws_size,
                              hipStream_t stream)
{
    const float* verts = (const float*)d_in[0];
    const int*   faces = (const int*)d_in[1];
    const float* Km    = (const float*)d_in[2];
    const float* Rm    = (const float*)d_in[3];
    const float* tm    = (const float*)d_in[4];
    const float* dm    = (const float*)d_in[5];
    float* out = (float*)d_out;

    int B  = in_sizes[2] / 9;          // intr is B*3*3
    int V  = in_sizes[0] / (3 * B);
    int F  = in_sizes[1] / (3 * B);
    int F2 = 2 * F;
    int npix = RASTN * RASTN;

    char* ws = (char*)d_ws;
    size_t off = 0;
    float4* rec = (float4*)(ws + off);
    off = (off + (size_t)B * F2 * 4 * sizeof(float4) + 255) & ~(size_t)255;
    uint2* sax = (uint2*)(ws + off);
    off = (off + (size_t)B * F2 * sizeof(uint2) + 255) & ~(size_t)255;
    unsigned short* stri = (unsigned short*)(ws + off);
    off = (off + (size_t)B * F2 * sizeof(unsigned short) + 255) & ~(size_t)255;
    float* uvzg = (float*)(ws + off);

    unsigned int* zbits = (unsigned int*)out;        // depth region doubles as zbuf
    float* mask = out + (size_t)B * npix;

    dim3 pgrid(B, NINITY);
    prep_sort_kernel<<<pgrid, 1024, 0, stream>>>(
        verts, faces, Km, Rm, tm, dm, rec, sax, stri, zbits, uvzg,
        V, F, F2, B, npix);
    dim3 rgrid(16, 16, B * SPLIT);
    raster_kernel<<<rgrid, 256, 0, stream>>>(rec, sax, stri, zbits, F2);
    post_kernel<<<B, 1024, 0, stream>>>((float*)zbits, mask, npix);
}

// Round 17
// 183.190 us; speedup vs baseline: 1.8140x; 1.1074x over previous
//
#include <hip/hip_runtime.h>
#include <cstdint>

#define RASTN 256
#define FARV 10.0f
#define FARBITS 0x41200000u   // bits of 10.0f
#define SPLIT 4               // measured optimum (R13: 4->103us; R14: 2->121us; R9: 8->150us)
#define NBUCK 1024            // counting-sort buckets; width 1/512 (exact dyadic)
#define NINITY 8              // extra prep blocks per batch for zbuf memset
#define POSTSEG 16            // post blocks per batch

__device__ __forceinline__ float gval(int i) {
    // g = 2*(i+0.5)/256 - 1  -- exact in f32 (multiples of 1/256)
    return (2.0f * ((float)i + 0.5f)) / 256.0f - 1.0f;
}

// ============ Kernel 1: project + prep + counting-sort + inits (grid B x NINITY) =
__global__ __launch_bounds__(1024) void prep_sort_kernel(
    const float* __restrict__ verts, const int* __restrict__ faces,
    const float* __restrict__ Km, const float* __restrict__ Rm,
    const float* __restrict__ tm, const float* __restrict__ dm,
    float4* __restrict__ rec, uint2* __restrict__ sax, unsigned short* __restrict__ stri,
    unsigned int* __restrict__ zbits, unsigned int* __restrict__ mm,
    unsigned int* __restrict__ cnt, float* __restrict__ uvzg,
    int V, int F, int F2, int B, int npix)
{
#pragma clang fp contract(off)
    __shared__ float s_uvz[1024*3];
    __shared__ unsigned int s_pk[4096];
    __shared__ unsigned short s_bk[4096];
    __shared__ unsigned int s_hist[NBUCK], s_cnt2[NBUCK];
    int b = blockIdx.x, y = blockIdx.y, tid = threadIdx.x;
    // ---- parallel z-buffer init: each y-block memsets 1/NINITY of this batch ----
    uint4* zb4 = (uint4*)(zbits + (size_t)b * npix);
    int n4 = npix >> 2;
    int sl0 = (n4 * y) / NINITY, sl1 = (n4 * (y + 1)) / NINITY;
    for (int i = sl0 + tid; i < sl1; i += 1024)
        zb4[i] = make_uint4(FARBITS, FARBITS, FARBITS, FARBITS);
    if (y > 0) return;
    if (tid == 0) { mm[2*b] = 0u; mm[2*b+1] = FARBITS; cnt[b] = 0u; }
    for (int i = tid; i < NBUCK; i += 1024) s_hist[i] = 0u;
    // ---- project (bit-exact replica of reference _project) ----
    bool inlds = (V <= 1024);
    const float* R = Rm + b*9; const float* K = Km + b*9;
    const float* t = tm + b*3; const float* d = dm + b*5;
    for (int v = tid; v < V; v += 1024) {
        float vx = verts[((size_t)b*V + v)*3+0];
        float vy = verts[((size_t)b*V + v)*3+1];
        float vz = verts[((size_t)b*V + v)*3+2];
        float cxm = ((vx*R[0] + vy*R[1]) + vz*R[2]) + t[0];
        float cym = ((vx*R[3] + vy*R[4]) + vz*R[5]) + t[1];
        float czm = ((vx*R[6] + vy*R[7]) + vz*R[8]) + t[2];
        float zd = czm + 1e-9f;
        float x_ = cxm / zd;
        float y_ = cym / zd;
        float k1 = d[0], k2 = d[1], p1 = d[2], p2 = d[3], k3 = d[4];
        float r2   = (x_*x_) + (y_*y_);
        float r2_2 = r2 * r2;
        float r2_3 = r2 * r2_2;
        float radial = ((1.0f + k1*r2) + k2*r2_2) + k3*r2_3;
        float x__ = ((x_*radial) + (((2.0f*p1)*x_)*y_)) + (p2*(r2 + 2.0f*(x_*x_)));
        float y__ = ((y_*radial) + (p1*(r2 + 2.0f*(y_*y_)))) + (((2.0f*p2)*x_)*y_);
        float up = ((x__*K[0]) + (y__*K[1])) + (1.0f*K[2]);
        float vp = ((x__*K[3]) + (y__*K[4])) + (1.0f*K[5]);
        vp = 256.0f - vp;
        float un = (2.0f*(up - 128.0f)) / 256.0f;
        float vn = (2.0f*(vp - 128.0f)) / 256.0f;
        if (inlds) { s_uvz[v*3+0]=un; s_uvz[v*3+1]=vn; s_uvz[v*3+2]=czm; }
        else { uvzg[((size_t)b*V+v)*3+0]=un; uvzg[((size_t)b*V+v)*3+1]=vn; uvzg[((size_t)b*V+v)*3+2]=czm; }
    }
    __syncthreads();
    const float* ub = inlds ? s_uvz : (uvzg + (size_t)b*V*3);
    const int* fb = faces + (size_t)b * F * 3;
    float4* rb = rec + (size_t)b * F2 * 4;
    bool stash = (F2 <= 4096);
    // ---- prep + histogram ----
    for (int j = tid; j < F2; j += 1024) {
        int i0, i1, i2;
        if (j < F) { i0 = fb[j*3+0]; i1 = fb[j*3+1]; i2 = fb[j*3+2]; }
        else { int jj = j - F; i0 = fb[jj*3+2]; i1 = fb[jj*3+1]; i2 = fb[jj*3+0]; }
        float ax = ub[i0*3+0], ay = ub[i0*3+1], az = ub[i0*3+2];
        float bx = ub[i1*3+0], by = ub[i1*3+1], bz = ub[i1*3+2];
        float cx = ub[i2*3+0], cy = ub[i2*3+1], cz = ub[i2*3+2];
        float den = (bx-ax)*(cy-ay) - (by-ay)*(cx-ax);
        bool ok = fabsf(den) > 1e-8f;
        float dens = ok ? den : 1.0f;
        bool alive = ok && (az > 1e-8f) && (bz > 1e-8f) && (cz > 1e-8f);
        float za = (az > 1e-8f) ? az : 1.0f;
        float zb = (bz > 1e-8f) ? bz : 1.0f;
        float zc = (cz > 1e-8f) ? cz : 1.0f;
        float mnx = fminf(ax, fminf(bx, cx));
        float mxx = fmaxf(ax, fmaxf(bx, cx));
        float mny = fminf(ay, fminf(by, cy));
        float mxy = fmaxf(ay, fmaxf(by, cy));
        float m = 1e-3f + 1e-6f*((fabsf(mnx)+fabsf(mxx))+(fabsf(mny)+fabsf(mxy)));
        mnx -= m; mxx += m; mny -= m; mxy += m;
        if (!(mxx >= -1.0f) || !(mnx <= 1.0f) || !(mxy >= -1.0f) || !(mny <= 1.0f)) alive = false;
        int ic0 = 1, ic1 = 0, ir0 = 1, ir1 = 0;
        float minz = 3e38f;
        if (alive) {
            float lx = fmaxf(mnx, -1.5f), hx = fminf(mxx, 1.5f);
            float ly = fmaxf(mny, -1.5f), hy = fminf(mxy, 1.5f);
            ic0 = (int)floorf((lx + 1.0f) * 128.0f - 0.5f);
            ic1 = (int)ceilf ((hx + 1.0f) * 128.0f - 0.5f);
            ir0 = (int)floorf((ly + 1.0f) * 128.0f - 0.5f);
            ir1 = (int)ceilf ((hy + 1.0f) * 128.0f - 0.5f);
            ic0 = ic0 < 0 ? 0 : ic0;  ir0 = ir0 < 0 ? 0 : ir0;
            ic1 = ic1 > 255 ? 255 : ic1;  ir1 = ir1 > 255 ? 255 : ir1;
            if (ic0 > ic1 || ir0 > ir1) { ic0 = 1; ic1 = 0; ir0 = 1; ir1 = 0; minz = 3e38f; }
            else minz = fminf(za, fminf(zb, zc)) * (1.0f - 4e-4f);  // conservative early-z key
        }
        float minzv = fminf(za, fminf(zb, zc));
        float maxzv = fmaxf(za, fmaxf(zb, zc));
        float rd = __builtin_amdgcn_rcpf(dens);
        float ra, rbz, rc;
        if (minzv > 1e-2f && maxzv < 100.0f * minzv) {
            ra  = __builtin_amdgcn_rcpf(za);
            rbz = __builtin_amdgcn_rcpf(zb);
            rc  = __builtin_amdgcn_rcpf(zc);
        } else {
            ra = rbz = rc = __builtin_huge_valf();   // filters disabled -> exact path
        }
        unsigned int pack = (unsigned int)(ic0 | (ic1 << 8) | (ir0 << 16) | (ir1 << 24));
        int bk = NBUCK - 1;                          // dead -> last bucket (huge key)
        if (minz < 1e30f) {
            bk = (int)(minz * 512.0f);               // floor; bucket LB = bk/512 exact
            bk = bk < 0 ? 0 : (bk > NBUCK-2 ? NBUCK-2 : bk);
        }
        size_t base = (size_t)j * 4;
        rb[base+0] = make_float4(cx, cy, by - cy, cx - bx);
        rb[base+1] = make_float4(cy - ay, ax - cx, rd, ra);
        rb[base+2] = make_float4(dens, za, zb, zc);
        rb[base+3] = make_float4(__uint_as_float(pack), minz, rbz, rc);
        atomicAdd(&s_hist[bk], 1u);
        if (stash) { s_pk[j] = pack; s_bk[j] = (unsigned short)bk; }
    }
    __syncthreads();
    // ---- exclusive prefix over NBUCK buckets (Hillis-Steele in LDS) ----
    for (int i = tid; i < NBUCK; i += 1024) s_cnt2[i] = s_hist[i];
    __syncthreads();
    for (int st = 1; st < NBUCK; st <<= 1) {
        unsigned int v = 0;
        if (tid < NBUCK && tid >= st) v = s_cnt2[tid - st];
        __syncthreads();
        if (tid < NBUCK && tid >= st) s_cnt2[tid] += v;
        __syncthreads();
    }
    if (tid < NBUCK) s_cnt2[tid] -= s_hist[tid];     // exclusive offsets
    __syncthreads();
    // ---- scatter (order within bucket arbitrary; key = bucket LB -> conservative) --
    uint2* sxb = sax + (size_t)b * F2;
    unsigned short* stb = stri + (size_t)b * F2;
    for (int j = tid; j < F2; j += 1024) {
        unsigned int pack; int bk;
        if (stash) { pack = s_pk[j]; bk = (int)s_bk[j]; }
        else {
            float4 q3 = rb[(size_t)j*4+3];
            pack = __float_as_uint(q3.x);
            float mz = q3.y;
            bk = NBUCK - 1;
            if (mz < 1e30f) { bk = (int)(mz * 512.0f); bk = bk < 0 ? 0 : (bk > NBUCK-2 ? NBUCK-2 : bk); }
        }
        float key = (bk == NBUCK-1) ? 3e38f : (float)bk * (1.0f/512.0f);  // exact dyadic LB
        int pos = (int)atomicAdd(&s_cnt2[bk], 1u);
        sxb[pos] = make_uint2(pack, __float_as_uint(key));
        stb[pos] = (unsigned short)j;
    }
}

// ============ Kernel 2: tile raster, SPLIT blocks/tile, shared per-pixel z =======
// (byte-identical to the R13 kernel measured at 103 us)
__global__ __launch_bounds__(256) void raster_kernel(
    const float4* __restrict__ rec, const uint2* __restrict__ sax,
    const unsigned short* __restrict__ stri, unsigned int* __restrict__ zbits,
    int F2)
{
#pragma clang fp contract(off)
    __shared__ float4 sh[256];                 // 64 tris x 4 records
    __shared__ float s_mz[64];
    __shared__ unsigned short s_list[256];
    __shared__ int s_wk[4], s_kk[4], s_wo[4];
    __shared__ int s_tot, s_kc;
    __shared__ float s_tzmax, s_red[4];
    int zz = blockIdx.z;
    int b = zz / SPLIT, sp = zz - b*SPLIT;
    int tc = blockIdx.x, tr = blockIdx.y;
    int tid = threadIdx.x, lane = tid & 63, wv = tid >> 6;
    int tx = tid & 15, ty = tid >> 4;
    int col = tc*16 + tx, row = tr*16 + ty;
    float X = gval(col), Y = gval(row);
    int pc0 = tc*16, pc1 = pc0+15, pr0 = tr*16, pr1 = pr0+15;
    const float4* rb = rec + (size_t)b * F2 * 4;
    const uint2* sxb = sax + (size_t)b * F2;
    const unsigned short* stb = stri + (size_t)b * F2;
    size_t pix = ((size_t)b*RASTN + row)*RASTN + col;
    unsigned int* zp_g = zbits + pix;
    float zmin = FARV;
    float pushed = FARV;     // min value known to already be in zbits[pix]
    if (tid == 0) s_tzmax = FARV;
    __syncthreads();
    int nch = (F2 + 256*SPLIT - 1) / (256*SPLIT);
    for (int c = 0; c < nch; ++c) {
        // rank interleaved at fine granularity: all splits converge on the front
        int s = (c*256 + tid)*SPLIT + sp;
        bool kp = false, sv = false; unsigned int tri = 0;
        if (s < F2) {
            uint2 a = sxb[s];
            float kf = __uint_as_float(a.y);
            kp = !(kf > s_tzmax);                  // conservative early-z (key <= minz)
            if (kp) {
                int pk = (int)a.x;
                int ic0 = pk & 255, ic1 = (pk >> 8) & 255;
                int ir0 = (pk >> 16) & 255, ir1 = (pk >> 24) & 255;
                sv = (ic0 <= ic1) && (ic0 <= pc1) && (ic1 >= pc0) && (ir0 <= pr1) && (ir1 >= pr0);
                if (sv) tri = stb[s];
            }
        }
        unsigned long long bs = __ballot(sv ? 1 : 0);
        unsigned long long bk = __ballot(kp ? 1 : 0);
        int pfx = __popcll(bs & ((1ull << lane) - 1ull));
        if (lane == 0) { s_wk[wv] = __popcll(bs); s_kk[wv] = __popcll(bk); }
        __syncthreads();
        if (tid == 0) {
            int acc = 0;
            for (int q = 0; q < 4; ++q) { s_wo[q] = acc; acc += s_wk[q]; }
            s_tot = acc;
            s_kc = s_kk[0] + s_kk[1] + s_kk[2] + s_kk[3];
        }
        __syncthreads();
        if (sv) s_list[s_wo[wv] + pfx] = (unsigned short)tri;
        int kcnt = s_kc, n = s_tot;
        if (kcnt == 0) break;   // keys non-decreasing: all remaining > tzmax
        for (int g = 0; g < n; g += 64) {
            __syncthreads();
            int cnt2 = (n - g) < 64 ? (n - g) : 64;
            if (tid < cnt2*4) {
                unsigned int t4 = s_list[g + (tid >> 2)];
                float4 f = rb[(size_t)t4*4 + (tid & 3)];
                sh[tid] = f;
                if ((tid & 3) == 3) s_mz[tid >> 2] = f.y;
            }
            __syncthreads();
            // ---- pull shared z: other splits' published mins tighten early-z.
            {
                float zg = __uint_as_float(__hip_atomic_load(
                    zp_g, __ATOMIC_RELAXED, __HIP_MEMORY_SCOPE_AGENT));
                pushed = fminf(pushed, zg);
                zmin = fminf(zmin, zg);
            }
            for (int i = 0; i < cnt2; ++i) {
                float mz = s_mz[i];
                if (mz > zmin) continue;           // per-pixel early-z (safe: zp >= mz)
                float4 q3 = sh[i*4+3];
                int pk = __float_as_int(q3.x);
                int ic0 = pk & 255, ic1 = (pk >> 8) & 255;
                int ir0 = (pk >> 16) & 255, ir1 = (pk >> 24) & 255;
                if (col < ic0 || col > ic1 || row < ir0 || row > ir1) continue;
                float4 q0 = sh[i*4+0];
                float4 q1 = sh[i*4+1];
                float xc = X - q0.x;
                float yc = Y - q0.y;
                float e0 = (q0.z*xc) + (q0.w*yc);  // w0 numerator, bit-exact vs ref
                float e1 = (q1.x*xc) + (q1.y*yc);  // w1 numerator
                float rd = q1.z;
                float sgn = copysignf(1.0f, rd);   // sign(rd) == sign(dens)
                float s0 = e0*sgn, s1 = e1*sgn;
                float w0a = e0*rd, w1a = e1*rd;    // approx w (filter only)
                float w2a = (1.0f - w0a) - w1a;
                float epsu = 1e-4f*((1.0f + fabsf(w0a)) + fabsf(w1a));
                if (s0 > -1e-30f && s1 > -1e-30f && w2a > -epsu) {
                    float inva = ((w0a*q1.w) + (w1a*q3.z)) + (w2a*q3.w);
                    float zpa = __builtin_amdgcn_rcpf(inva);
                    bool clearly = (s0 > 0.0f) && (s1 > 0.0f) && (w2a > epsu) && (inva > 1e-6f);
                    // clearly-valid + approx-zp above zmin provably cannot change the min
                    if (!clearly || zpa < zmin*1.001f) {
                        float4 q2 = sh[i*4+2];
                        float dens = q2.x;
                        float w0 = e0 / dens;      // IEEE div == ref
                        float w1 = e1 / dens;
                        float w2 = (1.0f - w0) - w1;
                        float inv = ((w0 / q2.y) + (w1 / q2.z)) + (w2 / q2.w);
                        if ((w0 >= 0.0f) && (w1 >= 0.0f) && (w2 >= 0.0f) && (inv > 1e-8f)) {
                            float zp = 1.0f / inv; // exact div == ref zp
                            zmin = fminf(zmin, zp);
                        }
                    }
                }
            }
            // ---- push improvement so other splits can skip their warm-up
            if (zmin < pushed) {
                atomicMin(zp_g, __float_as_uint(zmin));   // bit-monotone positive floats
                pushed = zmin;
            }
        }
        if (n > 0) {
            float zx = zmin;
            for (int o = 32; o; o >>= 1) zx = fmaxf(zx, __shfl_xor(zx, o));
            if (lane == 0) s_red[wv] = zx;
        }
        __syncthreads();
        if (n > 0 && tid == 0)
            s_tzmax = fminf(s_tzmax,
                fmaxf(fmaxf(s_red[0], s_red[1]), fmaxf(s_red[2], s_red[3])));
        __syncthreads();
    }
    if (zmin < pushed)
        atomicMin(zp_g, __float_as_uint(zmin));   // final publish
}

// ============ Kernel 3: post — B*16 blocks; per-batch arrival barrier, no fences =
// Phase 1: reduce own 4096-pixel segment (z in registers), write mask, fold into mm
//          via device-scope atomics; s_waitcnt vmcnt(0) (completion at coherent
//          point, NO cache-writeback fence) then bump the arrival counter.
// Phase 2: lane0 spins until all 16 arrivals, loads final mm, broadcasts; all
//          threads normalize from registers.
__global__ __launch_bounds__(256) void post_kernel(
    float* __restrict__ zdep, float* __restrict__ mask,
    unsigned int* __restrict__ mm, unsigned int* __restrict__ cnt, int npix)
{
#pragma clang fp contract(off)
    __shared__ float smx[4], smn[4];
    __shared__ float s_mx, s_mn;
    int b = (int)blockIdx.x / POSTSEG;
    int sid = (int)blockIdx.x - b * POSTSEG;
    int tid = threadIdx.x, lane = tid & 63, wv = tid >> 6;
    int seg = npix / POSTSEG;                  // 4096
    size_t base = (size_t)b * npix + (size_t)sid * seg;
    float zr[16];
    float vmx = 0.0f, vmn = FARV;
    int k = 0;
    for (int i = tid; i < seg; i += 256, ++k) {
        float z = zdep[base + i];
        zr[k] = z;
        mask[base + i] = (z < FARV) ? 1.0f : 0.0f;   // cover == any valid hit
        float nb = (z == FARV) ? 0.0f : z;           // (1-img_inf)*img
        vmx = fmaxf(vmx, nb);
        vmn = fminf(vmn, z);
    }
    for (int o = 32; o; o >>= 1) {
        vmx = fmaxf(vmx, __shfl_xor(vmx, o));
        vmn = fminf(vmn, __shfl_xor(vmn, o));
    }
    if (lane == 0) { smx[wv] = vmx; smn[wv] = vmn; }
    __syncthreads();
    if (tid == 0) {
        float bmx = fmaxf(fmaxf(smx[0], smx[1]), fmaxf(smx[2], smx[3]));
        float bmn = fminf(fminf(smn[0], smn[1]), fminf(smn[2], smn[3]));
        atomicMax(mm + 2*b,     __float_as_uint(bmx));   // device-scope, coherent point
        atomicMin(mm + 2*b + 1, __float_as_uint(bmn));
        // wait for MY atomics to complete at the coherent point (no cache flush)
        asm volatile("s_waitcnt vmcnt(0)" ::: "memory");
        __hip_atomic_fetch_add(cnt + b, 1u, __ATOMIC_RELAXED, __HIP_MEMORY_SCOPE_AGENT);
        // spin until all POSTSEG blocks of this batch arrived
        while (__hip_atomic_load(cnt + b, __ATOMIC_ACQUIRE, __HIP_MEMORY_SCOPE_AGENT)
               < (unsigned)POSTSEG)
            __builtin_amdgcn_s_sleep(8);
        s_mx = __uint_as_float(__hip_atomic_load(mm + 2*b,     __ATOMIC_RELAXED, __HIP_MEMORY_SCOPE_AGENT));
        s_mn = __uint_as_float(__hip_atomic_load(mm + 2*b + 1, __ATOMIC_RELAXED, __HIP_MEMORY_SCOPE_AGENT));
    }
    __syncthreads();
    float mx = s_mx, mn = s_mn;
    k = 0;
    for (int i = tid; i < seg; i += 256, ++k) {
        float z = zr[k];
        float nd = (mx - z) / ((mx - mn) + 1e-4f);
        float cv = nd;
        cv = (cv < 0.0f) ? 0.0f : cv;
        cv = (cv > 1.0f) ? 1.0f : cv;
        zdep[base + i] = cv;
    }
}

extern "C" void kernel_launch(void* const* d_in, const int* in_sizes, int n_in,
                              void* d_out, int out_size, void* d_ws, size_t ws_size,
                              hipStream_t stream)
{
    const float* verts = (const float*)d_in[0];
    const int*   faces = (const int*)d_in[1];
    const float* Km    = (const float*)d_in[2];
    const float* Rm    = (const float*)d_in[3];
    const float* tm    = (const float*)d_in[4];
    const float* dm    = (const float*)d_in[5];
    float* out = (float*)d_out;

    int B  = in_sizes[2] / 9;          // intr is B*3*3
    int V  = in_sizes[0] / (3 * B);
    int F  = in_sizes[1] / (3 * B);
    int F2 = 2 * F;
    int npix = RASTN * RASTN;

    char* ws = (char*)d_ws;
    size_t off = 0;
    float4* rec = (float4*)(ws + off);
    off = (off + (size_t)B * F2 * 4 * sizeof(float4) + 255) & ~(size_t)255;
    uint2* sax = (uint2*)(ws + off);
    off = (off + (size_t)B * F2 * sizeof(uint2) + 255) & ~(size_t)255;
    unsigned short* stri = (unsigned short*)(ws + off);
    off = (off + (size_t)B * F2 * sizeof(unsigned short) + 255) & ~(size_t)255;
    float* uvzg = (float*)(ws + off);
    off = (off + (size_t)B * V * 3 * sizeof(float) + 255) & ~(size_t)255;
    unsigned int* mm = (unsigned int*)(ws + off);
    off = (off + (size_t)B * 2 * sizeof(unsigned int) + 255) & ~(size_t)255;
    unsigned int* cnt = (unsigned int*)(ws + off);

    unsigned int* zbits = (unsigned int*)out;        // depth region doubles as zbuf
    float* mask = out + (size_t)B * npix;

    dim3 pgrid(B, NINITY);
    prep_sort_kernel<<<pgrid, 1024, 0, stream>>>(
        verts, faces, Km, Rm, tm, dm, rec, sax, stri, zbits, mm, cnt, uvzg,
        V, F, F2, B, npix);
    dim3 rgrid(16, 16, B * SPLIT);
    raster_kernel<<<rgrid, 256, 0, stream>>>(rec, sax, stri, zbits, F2);
    post_kernel<<<B * POSTSEG, 256, 0, stream>>>((float*)zbits, mask, mm, cnt, npix);
}

// Round 18
// 178.758 us; speedup vs baseline: 1.8590x; 1.0248x over previous
//
#include <hip/hip_runtime.h>
#include <cstdint>

#define RASTN 256
#define FARV 10.0f
#define FARBITS 0x41200000u   // bits of 10.0f
#define SPLIT 4               // measured optimum (R13: 4->103us; R14: 2->121us; R9: 8->150us)
#define NBUCK 1024            // counting-sort buckets; width 1/512 (exact dyadic)
#define NINITY 8              // extra prep blocks per batch for zbuf memset

__device__ __forceinline__ float gval(int i) {
    // g = 2*(i+0.5)/256 - 1  -- exact in f32 (multiples of 1/256)
    return (2.0f * ((float)i + 0.5f)) / 256.0f - 1.0f;
}

// ============ Kernel 1: project + prep + counting-sort + inits (grid B x NINITY) =
__global__ __launch_bounds__(1024) void prep_sort_kernel(
    const float* __restrict__ verts, const int* __restrict__ faces,
    const float* __restrict__ Km, const float* __restrict__ Rm,
    const float* __restrict__ tm, const float* __restrict__ dm,
    float4* __restrict__ rec, uint2* __restrict__ sax, unsigned short* __restrict__ stri,
    unsigned int* __restrict__ zbits, unsigned int* __restrict__ mm,
    float* __restrict__ uvzg, int V, int F, int F2, int B, int npix)
{
#pragma clang fp contract(off)
    __shared__ float s_uvz[1024*3];
    __shared__ unsigned int s_pk[4096];
    __shared__ unsigned short s_bk[4096];
    __shared__ unsigned int s_hist[NBUCK], s_cnt2[NBUCK];
    int b = blockIdx.x, y = blockIdx.y, tid = threadIdx.x;
    // ---- parallel z-buffer init: each y-block memsets 1/NINITY of this batch ----
    uint4* zb4 = (uint4*)(zbits + (size_t)b * npix);
    int n4 = npix >> 2;
    int sl0 = (n4 * y) / NINITY, sl1 = (n4 * (y + 1)) / NINITY;
    for (int i = sl0 + tid; i < sl1; i += 1024)
        zb4[i] = make_uint4(FARBITS, FARBITS, FARBITS, FARBITS);
    if (y > 0) return;
    if (tid == 0) { mm[2*b] = 0u; mm[2*b+1] = FARBITS; }  // minmax accumulators
    for (int i = tid; i < NBUCK; i += 1024) s_hist[i] = 0u;
    // ---- project (bit-exact replica of reference _project) ----
    bool inlds = (V <= 1024);
    const float* R = Rm + b*9; const float* K = Km + b*9;
    const float* t = tm + b*3; const float* d = dm + b*5;
    for (int v = tid; v < V; v += 1024) {
        float vx = verts[((size_t)b*V + v)*3+0];
        float vy = verts[((size_t)b*V + v)*3+1];
        float vz = verts[((size_t)b*V + v)*3+2];
        float cxm = ((vx*R[0] + vy*R[1]) + vz*R[2]) + t[0];
        float cym = ((vx*R[3] + vy*R[4]) + vz*R[5]) + t[1];
        float czm = ((vx*R[6] + vy*R[7]) + vz*R[8]) + t[2];
        float zd = czm + 1e-9f;
        float x_ = cxm / zd;
        float y_ = cym / zd;
        float k1 = d[0], k2 = d[1], p1 = d[2], p2 = d[3], k3 = d[4];
        float r2   = (x_*x_) + (y_*y_);
        float r2_2 = r2 * r2;
        float r2_3 = r2 * r2_2;
        float radial = ((1.0f + k1*r2) + k2*r2_2) + k3*r2_3;
        float x__ = ((x_*radial) + (((2.0f*p1)*x_)*y_)) + (p2*(r2 + 2.0f*(x_*x_)));
        float y__ = ((y_*radial) + (p1*(r2 + 2.0f*(y_*y_)))) + (((2.0f*p2)*x_)*y_);
        float up = ((x__*K[0]) + (y__*K[1])) + (1.0f*K[2]);
        float vp = ((x__*K[3]) + (y__*K[4])) + (1.0f*K[5]);
        vp = 256.0f - vp;
        float un = (2.0f*(up - 128.0f)) / 256.0f;
        float vn = (2.0f*(vp - 128.0f)) / 256.0f;
        if (inlds) { s_uvz[v*3+0]=un; s_uvz[v*3+1]=vn; s_uvz[v*3+2]=czm; }
        else { uvzg[((size_t)b*V+v)*3+0]=un; uvzg[((size_t)b*V+v)*3+1]=vn; uvzg[((size_t)b*V+v)*3+2]=czm; }
    }
    __syncthreads();
    const float* ub = inlds ? s_uvz : (uvzg + (size_t)b*V*3);
    const int* fb = faces + (size_t)b * F * 3;
    float4* rb = rec + (size_t)b * F2 * 4;
    bool stash = (F2 <= 4096);
    // ---- prep + histogram ----
    for (int j = tid; j < F2; j += 1024) {
        int i0, i1, i2;
        if (j < F) { i0 = fb[j*3+0]; i1 = fb[j*3+1]; i2 = fb[j*3+2]; }
        else { int jj = j - F; i0 = fb[jj*3+2]; i1 = fb[jj*3+1]; i2 = fb[jj*3+0]; }
        float ax = ub[i0*3+0], ay = ub[i0*3+1], az = ub[i0*3+2];
        float bx = ub[i1*3+0], by = ub[i1*3+1], bz = ub[i1*3+2];
        float cx = ub[i2*3+0], cy = ub[i2*3+1], cz = ub[i2*3+2];
        float den = (bx-ax)*(cy-ay) - (by-ay)*(cx-ax);
        bool ok = fabsf(den) > 1e-8f;
        float dens = ok ? den : 1.0f;
        bool alive = ok && (az > 1e-8f) && (bz > 1e-8f) && (cz > 1e-8f);
        float za = (az > 1e-8f) ? az : 1.0f;
        float zb = (bz > 1e-8f) ? bz : 1.0f;
        float zc = (cz > 1e-8f) ? cz : 1.0f;
        float mnx = fminf(ax, fminf(bx, cx));
        float mxx = fmaxf(ax, fmaxf(bx, cx));
        float mny = fminf(ay, fminf(by, cy));
        float mxy = fmaxf(ay, fmaxf(by, cy));
        float m = 1e-3f + 1e-6f*((fabsf(mnx)+fabsf(mxx))+(fabsf(mny)+fabsf(mxy)));
        mnx -= m; mxx += m; mny -= m; mxy += m;
        if (!(mxx >= -1.0f) || !(mnx <= 1.0f) || !(mxy >= -1.0f) || !(mny <= 1.0f)) alive = false;
        int ic0 = 1, ic1 = 0, ir0 = 1, ir1 = 0;
        float minz = 3e38f;
        if (alive) {
            float lx = fmaxf(mnx, -1.5f), hx = fminf(mxx, 1.5f);
            float ly = fmaxf(mny, -1.5f), hy = fminf(mxy, 1.5f);
            ic0 = (int)floorf((lx + 1.0f) * 128.0f - 0.5f);
            ic1 = (int)ceilf ((hx + 1.0f) * 128.0f - 0.5f);
            ir0 = (int)floorf((ly + 1.0f) * 128.0f - 0.5f);
            ir1 = (int)ceilf ((hy + 1.0f) * 128.0f - 0.5f);
            ic0 = ic0 < 0 ? 0 : ic0;  ir0 = ir0 < 0 ? 0 : ir0;
            ic1 = ic1 > 255 ? 255 : ic1;  ir1 = ir1 > 255 ? 255 : ir1;
            if (ic0 > ic1 || ir0 > ir1) { ic0 = 1; ic1 = 0; ir0 = 1; ir1 = 0; minz = 3e38f; }
            else minz = fminf(za, fminf(zb, zc)) * (1.0f - 4e-4f);  // conservative early-z key
        }
        float minzv = fminf(za, fminf(zb, zc));
        float maxzv = fmaxf(za, fmaxf(zb, zc));
        float rd = __builtin_amdgcn_rcpf(dens);
        float ra, rbz, rc;
        if (minzv > 1e-2f && maxzv < 100.0f * minzv) {
            ra  = __builtin_amdgcn_rcpf(za);
            rbz = __builtin_amdgcn_rcpf(zb);
            rc  = __builtin_amdgcn_rcpf(zc);
        } else {
            ra = rbz = rc = __builtin_huge_valf();   // filters disabled -> exact path
        }
        unsigned int pack = (unsigned int)(ic0 | (ic1 << 8) | (ir0 << 16) | (ir1 << 24));
        int bk = NBUCK - 1;                          // dead -> last bucket (huge key)
        if (minz < 1e30f) {
            bk = (int)(minz * 512.0f);               // floor; bucket LB = bk/512 exact
            bk = bk < 0 ? 0 : (bk > NBUCK-2 ? NBUCK-2 : bk);
        }
        size_t base = (size_t)j * 4;
        rb[base+0] = make_float4(cx, cy, by - cy, cx - bx);
        rb[base+1] = make_float4(cy - ay, ax - cx, rd, ra);
        rb[base+2] = make_float4(dens, za, zb, zc);
        rb[base+3] = make_float4(__uint_as_float(pack), minz, rbz, rc);
        atomicAdd(&s_hist[bk], 1u);
        if (stash) { s_pk[j] = pack; s_bk[j] = (unsigned short)bk; }
    }
    __syncthreads();
    // ---- exclusive prefix over NBUCK buckets (Hillis-Steele in LDS) ----
    for (int i = tid; i < NBUCK; i += 1024) s_cnt2[i] = s_hist[i];
    __syncthreads();
    for (int st = 1; st < NBUCK; st <<= 1) {
        unsigned int v = 0;
        if (tid < NBUCK && tid >= st) v = s_cnt2[tid - st];
        __syncthreads();
        if (tid < NBUCK && tid >= st) s_cnt2[tid] += v;
        __syncthreads();
    }
    if (tid < NBUCK) s_cnt2[tid] -= s_hist[tid];     // exclusive offsets
    __syncthreads();
    // ---- scatter (order within bucket arbitrary; key = bucket LB -> conservative) --
    uint2* sxb = sax + (size_t)b * F2;
    unsigned short* stb = stri + (size_t)b * F2;
    for (int j = tid; j < F2; j += 1024) {
        unsigned int pack; int bk;
        if (stash) { pack = s_pk[j]; bk = (int)s_bk[j]; }
        else {
            float4 q3 = rb[(size_t)j*4+3];
            pack = __float_as_uint(q3.x);
            float mz = q3.y;
            bk = NBUCK - 1;
            if (mz < 1e30f) { bk = (int)(mz * 512.0f); bk = bk < 0 ? 0 : (bk > NBUCK-2 ? NBUCK-2 : bk); }
        }
        float key = (bk == NBUCK-1) ? 3e38f : (float)bk * (1.0f/512.0f);  // exact dyadic LB
        int pos = (int)atomicAdd(&s_cnt2[bk], 1u);
        sxb[pos] = make_uint2(pack, __float_as_uint(key));
        stb[pos] = (unsigned short)j;
    }
}

// ============ Kernel 2: tile raster, SPLIT blocks/tile, shared per-pixel z =======
// R13 structure + SoA skip data: s_mz (minz) and s_bb (packed bbox) in separate 4B
// LDS arrays so mz-skips and bbox-rejects avoid the 16B q3 read entirely.
__global__ __launch_bounds__(256) void raster_kernel(
    const float4* __restrict__ rec, const uint2* __restrict__ sax,
    const unsigned short* __restrict__ stri, unsigned int* __restrict__ zbits,
    int F2)
{
#pragma clang fp contract(off)
    __shared__ float4 sh[256];                 // 64 tris x 4 records
    __shared__ float s_mz[64];
    __shared__ int s_bb[64];
    __shared__ unsigned short s_list[256];
    __shared__ int s_wk[4], s_kk[4], s_wo[4];
    __shared__ int s_tot, s_kc;
    __shared__ float s_tzmax, s_red[4];
    int zz = blockIdx.z;
    int b = zz / SPLIT, sp = zz - b*SPLIT;
    int tc = blockIdx.x, tr = blockIdx.y;
    int tid = threadIdx.x, lane = tid & 63, wv = tid >> 6;
    int tx = tid & 15, ty = tid >> 4;
    int col = tc*16 + tx, row = tr*16 + ty;
    float X = gval(col), Y = gval(row);
    int pc0 = tc*16, pc1 = pc0+15, pr0 = tr*16, pr1 = pr0+15;
    const float4* rb = rec + (size_t)b * F2 * 4;
    const uint2* sxb = sax + (size_t)b * F2;
    const unsigned short* stb = stri + (size_t)b * F2;
    size_t pix = ((size_t)b*RASTN + row)*RASTN + col;
    unsigned int* zp_g = zbits + pix;
    float zmin = FARV;
    float pushed = FARV;     // min value known to already be in zbits[pix]
    if (tid == 0) s_tzmax = FARV;
    __syncthreads();
    int nch = (F2 + 256*SPLIT - 1) / (256*SPLIT);
    for (int c = 0; c < nch; ++c) {
        // rank interleaved at fine granularity: all splits converge on the front
        int s = (c*256 + tid)*SPLIT + sp;
        bool kp = false, sv = false; unsigned int tri = 0;
        if (s < F2) {
            uint2 a = sxb[s];
            float kf = __uint_as_float(a.y);
            kp = !(kf > s_tzmax);                  // conservative early-z (key <= minz)
            if (kp) {
                int pk = (int)a.x;
                int ic0 = pk & 255, ic1 = (pk >> 8) & 255;
                int ir0 = (pk >> 16) & 255, ir1 = (pk >> 24) & 255;
                sv = (ic0 <= ic1) && (ic0 <= pc1) && (ic1 >= pc0) && (ir0 <= pr1) && (ir1 >= pr0);
                if (sv) tri = stb[s];
            }
        }
        unsigned long long bs = __ballot(sv ? 1 : 0);
        unsigned long long bk = __ballot(kp ? 1 : 0);
        int pfx = __popcll(bs & ((1ull << lane) - 1ull));
        if (lane == 0) { s_wk[wv] = __popcll(bs); s_kk[wv] = __popcll(bk); }
        __syncthreads();
        if (tid == 0) {
            int acc = 0;
            for (int q = 0; q < 4; ++q) { s_wo[q] = acc; acc += s_wk[q]; }
            s_tot = acc;
            s_kc = s_kk[0] + s_kk[1] + s_kk[2] + s_kk[3];
        }
        __syncthreads();
        if (sv) s_list[s_wo[wv] + pfx] = (unsigned short)tri;
        int kcnt = s_kc, n = s_tot;
        if (kcnt == 0) break;   // keys non-decreasing: all remaining > tzmax
        for (int g = 0; g < n; g += 64) {
            __syncthreads();
            int cnt2 = (n - g) < 64 ? (n - g) : 64;
            if (tid < cnt2*4) {
                unsigned int t4 = s_list[g + (tid >> 2)];
                float4 f = rb[(size_t)t4*4 + (tid & 3)];
                sh[tid] = f;
                if ((tid & 3) == 3) {
                    s_mz[tid >> 2] = f.y;
                    s_bb[tid >> 2] = __float_as_int(f.x);
                }
            }
            __syncthreads();
            // ---- pull shared z: other splits' published mins tighten early-z.
            // zbits only decreases; pulled >= final -> skips are conservative.
            {
                float zg = __uint_as_float(__hip_atomic_load(
                    zp_g, __ATOMIC_RELAXED, __HIP_MEMORY_SCOPE_AGENT));
                pushed = fminf(pushed, zg);
                zmin = fminf(zmin, zg);
            }
            for (int i = 0; i < cnt2; ++i) {
                float mz = s_mz[i];                // 4B broadcast: cheap mz skip
                if (mz > zmin) continue;           // per-pixel early-z (safe: zp >= mz)
                int pk = s_bb[i];                  // 4B broadcast: cheap bbox reject
                int ic0 = pk & 255, ic1 = (pk >> 8) & 255;
                int ir0 = (pk >> 16) & 255, ir1 = (pk >> 24) & 255;
                if (col < ic0 || col > ic1 || row < ir0 || row > ir1) continue;
                float4 q0 = sh[i*4+0];
                float4 q1 = sh[i*4+1];
                float xc = X - q0.x;
                float yc = Y - q0.y;
                float e0 = (q0.z*xc) + (q0.w*yc);  // w0 numerator, bit-exact vs ref
                float e1 = (q1.x*xc) + (q1.y*yc);  // w1 numerator
                float rd = q1.z;
                float sgn = copysignf(1.0f, rd);   // sign(rd) == sign(dens)
                float s0 = e0*sgn, s1 = e1*sgn;
                float w0a = e0*rd, w1a = e1*rd;    // approx w (filter only)
                float w2a = (1.0f - w0a) - w1a;
                float epsu = 1e-4f*((1.0f + fabsf(w0a)) + fabsf(w1a));
                if (s0 > -1e-30f && s1 > -1e-30f && w2a > -epsu) {
                    float4 q3 = sh[i*4+3];         // rcp(zb), rcp(zc) for candidates only
                    float inva = ((w0a*q1.w) + (w1a*q3.z)) + (w2a*q3.w);
                    float zpa = __builtin_amdgcn_rcpf(inva);
                    bool clearly = (s0 > 0.0f) && (s1 > 0.0f) && (w2a > epsu) && (inva > 1e-6f);
                    // clearly-valid + approx-zp above zmin (w/ margin) provably
                    // cannot change the exact min -> skip the 6 IEEE divides
                    if (!clearly || zpa < zmin*1.001f) {
                        float4 q2 = sh[i*4+2];
                        float dens = q2.x;
                        float w0 = e0 / dens;      // IEEE div == ref
                        float w1 = e1 / dens;
                        float w2 = (1.0f - w0) - w1;
                        float inv = ((w0 / q2.y) + (w1 / q2.z)) + (w2 / q2.w);
                        if ((w0 >= 0.0f) && (w1 >= 0.0f) && (w2 >= 0.0f) && (inv > 1e-8f)) {
                            float zp = 1.0f / inv; // exact div == ref zp
                            zmin = fminf(zmin, zp);
                        }
                    }
                }
            }
            // ---- push improvement so other splits can skip their warm-up
            if (zmin < pushed) {
                atomicMin(zp_g, __float_as_uint(zmin));   // bit-monotone positive floats
                pushed = zmin;
            }
        }
        if (n > 0) {
            // tile zmax refresh: only shrinks -> stays a conservative upper bound
            float zx = zmin;
            for (int o = 32; o; o >>= 1) zx = fmaxf(zx, __shfl_xor(zx, o));
            if (lane == 0) s_red[wv] = zx;
        }
        __syncthreads();
        if (n > 0 && tid == 0)
            s_tzmax = fminf(s_tzmax,
                fmaxf(fmaxf(s_red[0], s_red[1]), fmaxf(s_red[2], s_red[3])));
        __syncthreads();
    }
    if (zmin < pushed)
        atomicMin(zp_g, __float_as_uint(zmin));   // final publish
}

// ============ Kernel 3: per-batch minmax reduction + mask write ==================
__global__ __launch_bounds__(256) void minmax_kernel(
    const float* __restrict__ zbuf, float* __restrict__ mask,
    unsigned int* __restrict__ mm, int npix, int seg)
{
    __shared__ float smx[4], smn[4];
    int b = blockIdx.y;
    size_t base = (size_t)b * npix + (size_t)blockIdx.x * seg;
    const float* p = zbuf + base;
    float* mk = mask + base;
    int lane = threadIdx.x & 63, wv = threadIdx.x >> 6;
    float vmx = 0.0f, vmn = FARV;
    for (int i = threadIdx.x; i < seg; i += 256) {
        float z = p[i];
        mk[i] = (z < FARV) ? 1.0f : 0.0f;    // cover == any valid hit (z < FAR)
        float nb = (z == FARV) ? 0.0f : z;   // (1-img_inf)*img
        vmx = fmaxf(vmx, nb);
        vmn = fminf(vmn, z);
    }
    for (int o = 32; o; o >>= 1) {
        vmx = fmaxf(vmx, __shfl_xor(vmx, o));
        vmn = fminf(vmn, __shfl_xor(vmn, o));
    }
    if (lane == 0) { smx[wv] = vmx; smn[wv] = vmn; }
    __syncthreads();
    if (threadIdx.x == 0) {
        float bmx = fmaxf(fmaxf(smx[0], smx[1]), fmaxf(smx[2], smx[3]));
        float bmn = fminf(fminf(smn[0], smn[1]), fminf(smn[2], smn[3]));
        atomicMax(mm + 2*b,     __float_as_uint(bmx));   // positive floats: bit-monotone
        atomicMin(mm + 2*b + 1, __float_as_uint(bmn));
    }
}

// ============ Kernel 4: normalize depth in place =================================
__global__ __launch_bounds__(256) void final_kernel(
    float* __restrict__ zdep, const unsigned int* __restrict__ mm, int npix, int total)
{
#pragma clang fp contract(off)
    int idx = blockIdx.x*256 + threadIdx.x;
    if (idx >= total) return;
    int b = idx / npix;
    float mx = __uint_as_float(mm[2*b]);
    float mn = __uint_as_float(mm[2*b + 1]);
    float z = zdep[idx];
    float nd = (mx - z) / ((mx - mn) + 1e-4f);
    float cv = nd;
    cv = (cv < 0.0f) ? 0.0f : cv;
    cv = (cv > 1.0f) ? 1.0f : cv;
    zdep[idx] = cv;
}

extern "C" void kernel_launch(void* const* d_in, const int* in_sizes, int n_in,
                              void* d_out, int out_size, void* d_ws, size_t ws_size,
                              hipStream_t stream)
{
    const float* verts = (const float*)d_in[0];
    const int*   faces = (const int*)d_in[1];
    const float* Km    = (const float*)d_in[2];
    const float* Rm    = (const float*)d_in[3];
    const float* tm    = (const float*)d_in[4];
    const float* dm    = (const float*)d_in[5];
    float* out = (float*)d_out;

    int B  = in_sizes[2] / 9;          // intr is B*3*3
    int V  = in_sizes[0] / (3 * B);
    int F  = in_sizes[1] / (3 * B);
    int F2 = 2 * F;
    int npix = RASTN * RASTN;

    char* ws = (char*)d_ws;
    size_t off = 0;
    float4* rec = (float4*)(ws + off);
    off = (off + (size_t)B * F2 * 4 * sizeof(float4) + 255) & ~(size_t)255;
    uint2* sax = (uint2*)(ws + off);
    off = (off + (size_t)B * F2 * sizeof(uint2) + 255) & ~(size_t)255;
    unsigned short* stri = (unsigned short*)(ws + off);
    off = (off + (size_t)B * F2 * sizeof(unsigned short) + 255) & ~(size_t)255;
    float* uvzg = (float*)(ws + off);
    off = (off + (size_t)B * V * 3 * sizeof(float) + 255) & ~(size_t)255;
    unsigned int* mm = (unsigned int*)(ws + off);

    unsigned int* zbits = (unsigned int*)out;        // depth region doubles as zbuf
    float* mask = out + (size_t)B * npix;

    dim3 pgrid(B, NINITY);
    prep_sort_kernel<<<pgrid, 1024, 0, stream>>>(
        verts, faces, Km, Rm, tm, dm, rec, sax, stri, zbits, mm, uvzg,
        V, F, F2, B, npix);
    dim3 rgrid(16, 16, B * SPLIT);
    raster_kernel<<<rgrid, 256, 0, stream>>>(rec, sax, stri, zbits, F2);
    int seg = npix / 16;
    dim3 mgrid(16, B);
    minmax_kernel<<<mgrid, 256, 0, stream>>>((float*)zbits, mask, mm, npix, seg);
    final_kernel<<<(B * npix + 255) / 256, 256, 0, stream>>>((float*)zbits, mm, npix, B * npix);
}